// Round 11
// baseline (1423.528 us; speedup 1.0000x reference)
//
#include <hip/hip_runtime.h>

#define PI_F 3.14159265358979323846f

#define NCH   1000
#define NPTS  30000
#define NHALF 15000      // NPTS/2 packed complex samples
#define NFFT  32768      // complex FFT length (real length 65536)
#define NBF32 1024       // butterflies per channel per radix-32 pass (NFFT/32)
#define STR   32770      // per-channel stride in complex elements
#define XCOR  59999

#define UC 0.99518472667219693f
#define US 0.09801714032956060f

__device__ __forceinline__ float2 cadd(float2 a, float2 b){ return make_float2(a.x+b.x, a.y+b.y); }
__device__ __forceinline__ float2 csub(float2 a, float2 b){ return make_float2(a.x-b.x, a.y-b.y); }
__device__ __forceinline__ float2 cmul(float2 a, float2 b){ return make_float2(a.x*b.x - a.y*b.y, a.x*b.y + a.y*b.x); }

template<int S>
__device__ __forceinline__ float2 mulIs(float2 z){ return make_float2(-(float)S*z.y, (float)S*z.x); }

// 8-point DFT, ω = e^{S*2πi/8}
template<int S>
__device__ __forceinline__ void dft8(float2 v[8]){
  const float r2 = 0.7071067811865476f;
  const float sf = (float)S;
  float2 ea=cadd(v[0],v[4]), eb=csub(v[0],v[4]);
  float2 ec=cadd(v[2],v[6]), ed=csub(v[2],v[6]);
  float2 oa=cadd(v[1],v[5]), ob=csub(v[1],v[5]);
  float2 oc=cadd(v[3],v[7]), od=csub(v[3],v[7]);
  float2 ied=mulIs<S>(ed), iod=mulIs<S>(od);
  float2 E0=cadd(ea,ec), E2=csub(ea,ec), E1=cadd(eb,ied), E3=csub(eb,ied);
  float2 O0=cadd(oa,oc), O2=csub(oa,oc), O1=cadd(ob,iod), O3=csub(ob,iod);
  float2 T1 = make_float2(r2*(O1.x - sf*O1.y), r2*(O1.y + sf*O1.x));
  float2 T2 = mulIs<S>(O2);
  float2 T3 = make_float2(r2*(-O3.x - sf*O3.y), r2*(sf*O3.x - O3.y));
  v[0]=cadd(E0,O0); v[4]=csub(E0,O0);
  v[1]=cadd(E1,T1); v[5]=csub(E1,T1);
  v[2]=cadd(E2,T2); v[6]=csub(E2,T2);
  v[3]=cadd(E3,T3); v[7]=csub(E3,T3);
}

template<int S>
__device__ __forceinline__ void dft4(float2 v[4]){
  float2 t0=cadd(v[0],v[2]), t1=csub(v[0],v[2]);
  float2 t2=cadd(v[1],v[3]), t3=mulIs<S>(csub(v[1],v[3]));
  v[0]=cadd(t0,t2); v[2]=csub(t0,t2);
  v[1]=cadd(t1,t3); v[3]=csub(t1,t3);
}

// 32-point DFT in registers
template<int S>
__device__ __forceinline__ void dft32(float2 v[32]){
  constexpr float TC[22] = {
    1.f, 0.98078528040323044f, 0.92387953251128674f, 0.83146961230254524f,
    0.70710678118654757f, 0.55557023301960218f, 0.38268343236508978f, 0.19509032201612825f,
    0.f, -0.19509032201612825f, -0.38268343236508978f, -0.55557023301960218f,
    -0.70710678118654757f, -0.83146961230254524f, -0.92387953251128674f, -0.98078528040323044f,
    -1.f, -0.98078528040323044f, -0.92387953251128674f, -0.83146961230254524f,
    -0.70710678118654757f, -0.55557023301960218f };
  constexpr float TS[22] = {
    0.f, 0.19509032201612825f, 0.38268343236508978f, 0.55557023301960218f,
    0.70710678118654757f, 0.83146961230254524f, 0.92387953251128674f, 0.98078528040323044f,
    1.f, 0.98078528040323044f, 0.92387953251128674f, 0.83146961230254524f,
    0.70710678118654757f, 0.55557023301960218f, 0.38268343236508978f, 0.19509032201612825f,
    0.f, -0.19509032201612825f, -0.38268343236508978f, -0.55557023301960218f,
    -0.70710678118654757f, -0.83146961230254524f };
  float2 y[4][8];
  #pragma unroll
  for (int b = 0; b < 4; ++b)
    #pragma unroll
    for (int a = 0; a < 8; ++a) y[b][a] = v[4*a + b];
  #pragma unroll
  for (int b = 0; b < 4; ++b) dft8<S>(y[b]);
  #pragma unroll
  for (int b = 1; b < 4; ++b)
    #pragma unroll
    for (int k1 = 1; k1 < 8; ++k1) {
      int m = b*k1;
      float2 w = make_float2(TC[m], (float)S * TS[m]);
      y[b][k1] = cmul(y[b][k1], w);
    }
  #pragma unroll
  for (int k1 = 0; k1 < 8; ++k1) {
    float2 z[4] = { y[0][k1], y[1][k1], y[2][k1], y[3][k1] };
    dft4<S>(z);
    #pragma unroll
    for (int k2 = 0; k2 < 4; ++k2) v[k1 + 8*k2] = z[k2];
  }
}

template<int S>
__device__ __forceinline__ void stage_twiddle32(float2 v[32], float ang){
  float s1,c1,s8,c8;
  __sincosf(ang, &s1, &c1);
  __sincosf(8.f*ang, &s8, &c8);
  float2 w1 = make_float2(c1, s1), w8 = make_float2(c8, s8);
  float2 w16 = cmul(w8, w8), w24 = cmul(w16, w8);
  float2 base[4] = { make_float2(1.f, 0.f), w8, w16, w24 };
  #pragma unroll
  for (int m = 0; m < 4; ++m) {
    float2 wr = base[m];
    if (m > 0) v[8*m] = cmul(v[8*m], wr);
    #pragma unroll
    for (int l = 1; l < 8; ++l) { wr = cmul(wr, w1); v[8*m+l] = cmul(v[8*m+l], wr); }
  }
}

// ========== FWD FUSED v2: stages LG0 + LG5, half-slot LDS (33.8 KB) for occupancy ==========
// Stage-1 thread t: butterfly j1 = 8b + (t&7) + 32*(t>>3); LDS slot-major lds[slot*264 + t].
// Stage-2 thread t: (d = t&7, jm = t>>3), butterfly j2 = 256b + 32d + jm; reads slot jm of
// stage-1 threads d+8r. Waves 0-1 (jm<16) consume slots 0..15, then slots 16..31 are written
// and waves 2-3 (jm>=16) consume them. Same verified math as round-7 fft_fwd_fused.
__global__ __launch_bounds__(256) void fft_fwd_fused2(const float* __restrict__ d1, const float* __restrict__ d2,
                                                      float2* __restrict__ out, int cb, int ch0)
{
  __shared__ float2 lds[16*264];   // 33,792 B
  const int bid = blockIdx.x;
  const int c = bid >> 2, b = bid & 3;
  const int t = threadIdx.x;
  const float* src = (c < cb) ? (d1 + (size_t)(ch0 + c) * NPTS)
                              : (d2 + (size_t)(ch0 + c - cb) * NPTS);
  const float2* src2 = reinterpret_cast<const float2*>(src);

  // ---- stage 1 (LG0), fused real-pair packing + zero pad ----
  const int j1 = 8*b + (t & 7) + 32*(t >> 3);
  float2 v[32];
  #pragma unroll
  for (int r = 0; r < 32; ++r) {
    int m = j1 + (r << 10);
    v[r] = (m < NHALF) ? src2[m] : make_float2(0.f, 0.f);
  }
  dft32<-1>(v);

  // ---- half A: slots 0..15 ----
  #pragma unroll
  for (int rr = 0; rr < 16; ++rr) lds[rr*264 + t] = v[rr];
  __syncthreads();
  if (t < 128) {
    const int d = t & 7, jm = t >> 3;                    // jm in [0,16)
    float2 w[32];
    #pragma unroll
    for (int r = 0; r < 32; ++r) w[r] = lds[jm*264 + d + 8*r];
    stage_twiddle32<-1>(w, -(2.0f*PI_F) * (float)jm * (1.0f/1024.0f));
    dft32<-1>(w);
    float2* dst = out + (size_t)c * STR + ((size_t)(8*b + d) << 10) + jm;
    #pragma unroll
    for (int r = 0; r < 32; ++r) dst[(size_t)(r << 5)] = w[r];
  }
  __syncthreads();

  // ---- half B: slots 16..31 ----
  #pragma unroll
  for (int rr = 16; rr < 32; ++rr) lds[(rr-16)*264 + t] = v[rr];
  __syncthreads();
  if (t >= 128) {
    const int d = t & 7, jm = t >> 3;                    // jm in [16,32)
    float2 w[32];
    #pragma unroll
    for (int r = 0; r < 32; ++r) w[r] = lds[(jm-16)*264 + d + 8*r];
    stage_twiddle32<-1>(w, -(2.0f*PI_F) * (float)jm * (1.0f/1024.0f));
    dft32<-1>(w);
    float2* dst = out + (size_t)c * STR + ((size_t)(8*b + d) << 10) + jm;
    #pragma unroll
    for (int r = 0; r < 32; ++r) dst[(size_t)(r << 5)] = w[r];
  }
}

// ---------- generic Stockham radix-32 pass, Ns = 2^LG ----------
template<int LG, int S>
__global__ __launch_bounds__(256) void fft_pass32(const float2* __restrict__ in, float2* __restrict__ out)
{
  int tid = blockIdx.x*256 + threadIdx.x;
  int c = tid >> 10;
  int j = tid & (NBF32-1);
  const float2* src = in + (size_t)c * STR;
  float2 v[32];
  #pragma unroll
  for (int r = 0; r < 32; ++r) v[r] = src[j + (r << 10)];
  constexpr int NS = 1 << LG;
  int jm = j & (NS - 1);
  if constexpr (LG > 0) {
    float ang = (float)S * (2.0f*PI_F) * (float)jm / (float)(NS*32);
    stage_twiddle32<S>(v, ang);
  }
  dft32<S>(v);
  int idxD = ((j >> LG) << (LG+5)) + jm;
  float2* dst = out + (size_t)c * STR + idxD;
  #pragma unroll
  for (int r = 0; r < 32; ++r) dst[(size_t)(r << LG)] = v[r];
}

// ---------- whitening (round-2 verified): rfft unpack + running-abs-mean + tapers, in place ----------
__device__ __forceinline__ int padidx(int m){ return m + (m >> 5); }

__global__ __launch_bounds__(1024) void whiten_kernel(float2* __restrict__ buf)
{
  const int ch = blockIdx.x;
  const int t  = threadIdx.x;
  float2* Z = buf + (size_t)ch * STR;
  __shared__ float s[33793];     // 32769 magnitudes, padded every 32
  __shared__ float wsums[16];

  float2 X[33];
  #pragma unroll
  for (int i = 0; i < 33; ++i) {
    int k = i*1024 + t;
    if (i < 32 || t == 0) {
      float2 zk = Z[k & (NFFT-1)];
      float2 zn = Z[(NFFT - k) & (NFFT-1)];
      float2 xe = make_float2(0.5f*(zk.x+zn.x), 0.5f*(zk.y-zn.y));
      float2 xh = make_float2(0.5f*(zk.x-zn.x), 0.5f*(zk.y+zn.y));
      float2 xo = make_float2(xh.y, -xh.x);
      float ang = -PI_F * (float)k * (1.0f/32768.0f);
      float sn, cs; __sincosf(ang, &sn, &cs);
      float2 w = make_float2(cs, sn);
      X[i] = cadd(xe, cmul(w, xo));
      s[padidx(k)] = sqrtf(X[i].x*X[i].x + X[i].y*X[i].y);
    }
  }
  __syncthreads();

  const int base = t*32;
  float sum = 0.f;
  #pragma unroll
  for (int q = 0; q < 32; ++q) sum += s[padidx(base+q)];
  if (t == 1023) sum += s[padidx(32768)];
  const int lane = t & 63, wid = t >> 6;
  float v = sum;
  #pragma unroll
  for (int off = 1; off < 64; off <<= 1) {
    float u = __shfl_up(v, off);
    if (lane >= off) v += u;
  }
  if (lane == 63) wsums[wid] = v;
  __syncthreads();
  float wexcl = 0.f;
  for (int w = 0; w < 16; ++w) wexcl += (w < wid) ? wsums[w] : 0.f;
  float run = wexcl + (v - sum);
  #pragma unroll
  for (int q = 0; q < 32; ++q) {
    int idx = padidx(base+q);
    run += s[idx];
    s[idx] = run;
  }
  if (t == 1023) { int idx = padidx(32768); run += s[idx]; s[idx] = run; }
  __syncthreads();

  const float a0 = s[padidx(0)];
  const float alast = s[padidx(32768)] - s[padidx(32767)];
  #pragma unroll
  for (int i = 0; i < 33; ++i) {
    int k = i*1024 + t;
    if (i < 32 || t == 0) {
      int hi = k + 327; if (hi > 32768) hi = 32768;
      int lom1 = k - 328;
      float Shi = s[padidx(hi)];
      float Slo = (lom1 >= 0) ? s[padidx(lom1)] : 0.f;
      float lc = (k < 327) ? (float)(327 - k) : 0.f;
      float rc = (k > 32441) ? (float)(k - 32441) : 0.f;
      float smoothed = (lc*a0 + (Shi - Slo) + rc*alast) * (1.0f/655.0f);
      float2 wv;
      if (smoothed > 0.f) {
        float inv = 1.0f / smoothed;
        wv = make_float2(X[i].x*inv, X[i].y*inv);
      } else wv = make_float2(0.f, 0.f);
      float tp = 1.0f;
      if (k < 131)        { float th = (float)k * (PI_F/260.0f);           float sn = __sinf(th); tp = sn*sn; }
      else if (k >= 13108){ float th = (float)(k-13108) * (PI_F/39320.0f); float cs = __cosf(th); tp = cs*cs; }
      wv.x *= tp; wv.y *= tp;
      Z[k] = wv;
    }
  }
}

// ================= CROSS_INV0 (round-7 verified, LDS-free): cross + irfft pack + inverse stage-0 =================
__global__ __launch_bounds__(256) void cross_inv0(const float2* __restrict__ W,
                                                  float2* __restrict__ out0, int cb)
{
  int tid = blockIdx.x*256 + threadIdx.x;
  int c = tid >> 10;
  int j = tid & 1023;
  const float2* W1 = W + (size_t)c * STR;
  const float2* W2 = W + (size_t)(cb + c) * STR;
  const float scale = 1.0f/32768.0f;
  float sj, cj; __sincosf(PI_F*(float)j*(1.0f/32768.0f), &sj, &cj);
  float2 pw = make_float2(cj, sj);                 // e^{+i pi m/32768}, m = j+1024r
  const float2 pstep = make_float2(UC, US);        // e^{+i pi/32}
  float2 v[32];
  #pragma unroll
  for (int r = 0; r < 32; ++r) {
    int m = j + (r << 10);
    int mm = 32768 - m;                            // in [1, 32768]; W[32768] stored
    float2 A  = W1[m],  B  = W2[m];
    float2 Am = W1[mm], Bm = W2[mm];
    float2 Ck = make_float2(A.x*B.x + A.y*B.y,     A.x*B.y - A.y*B.x);     // conj(W1)W2
    float2 Cn = make_float2(Am.x*Bm.x + Am.y*Bm.y, Am.x*Bm.y - Am.y*Bm.x);
    float2 xe = make_float2(0.5f*(Ck.x+Cn.x), 0.5f*(Ck.y-Cn.y));
    float2 d  = make_float2(0.5f*(Ck.x-Cn.x), 0.5f*(Ck.y+Cn.y));
    float2 xo = cmul(pw, d);
    v[r] = make_float2((xe.x - xo.y)*scale, (xe.y + xo.x)*scale);
    pw = cmul(pw, pstep);
  }
  dft32<1>(v);
  float4* o4 = reinterpret_cast<float4*>(out0 + (size_t)c * STR + (size_t)j * 32);
  #pragma unroll
  for (int r = 0; r < 32; r += 2)
    o4[r>>1] = make_float4(v[r].x, v[r].y, v[r+1].x, v[r+1].y);
}

// ========== INV FUSED v3: stages LG5 + LG10 + roll + slice, half-slot LDS (33.8 KB) ==========
// l-grouped (no redundancy, round-10 verified math). Block (c,b) owns l in [8b,8b+8).
// Stage-1 thread (li=t&7, s=t>>3): butterfly j1 = 8b+li+32s, LDS slot-major lds[slot*264 + t].
// Stage-2 thread (li2=t&7, q=t>>3): butterfly j2 = 8b+li2+32q reads slot q of threads li2+8*r2.
// Waves 0-1 (q<16) consume slots 0..15; then slots 16..31 written; waves 2-3 consume.
__global__ __launch_bounds__(256) void fft_inv_fused3(const float2* __restrict__ in,
                                                      float* __restrict__ out, int ch0)
{
  __shared__ float2 lds[16*264];   // 33,792 B
  const int c = blockIdx.x;
  const int b = blockIdx.y;
  const int t = threadIdx.x;
  const int li = t & 7, s = t >> 3;
  const float2* src = in + (size_t)c * STR;

  // ---- stage 1: LG5 butterfly j1 = 8b + li + 32s ----
  const int j1 = 8*b + li + 32*s;
  float2 v[32];
  #pragma unroll
  for (int r = 0; r < 32; ++r) v[r] = src[j1 + (r << 10)];
  stage_twiddle32<1>(v, (2.0f*PI_F) * (float)(8*b + li) * (1.0f/1024.0f));
  dft32<1>(v);

  // ---- half A: slots 0..15 ----
  #pragma unroll
  for (int rr = 0; rr < 16; ++rr) lds[rr*264 + t] = v[rr];
  __syncthreads();
  if (t < 128) {
    const int li2 = t & 7, q = t >> 3;        // q in [0,16)
    const int j2 = 8*b + li2 + 32*q;
    float2 w[32];
    #pragma unroll
    for (int r2 = 0; r2 < 32; ++r2) w[r2] = lds[q*264 + li2 + 8*r2];
    stage_twiddle32<1>(w, (2.0f*PI_F) * (float)j2 * (1.0f/32768.0f));
    dft32<1>(w);
    float* o = out + (size_t)(ch0 + c) * XCOR;
    #pragma unroll
    for (int r = 0; r < 32; ++r) {
      int n = j2 + (r << 10);
      int m = 2*n;
      int j1o = (m <= 29999) ? (m + 29999) : ((m >= 35537) ? (m - 35537) : -1);
      if (j1o >= 0) o[j1o] = w[r].x;
      int m2 = m + 1;
      int j2o = (m2 <= 29999) ? (m2 + 29999) : ((m2 >= 35537) ? (m2 - 35537) : -1);
      if (j2o >= 0) o[j2o] = w[r].y;
    }
  }
  __syncthreads();

  // ---- half B: slots 16..31 ----
  #pragma unroll
  for (int rr = 16; rr < 32; ++rr) lds[(rr-16)*264 + t] = v[rr];
  __syncthreads();
  if (t >= 128) {
    const int li2 = t & 7, q = t >> 3;        // q in [16,32)
    const int j2 = 8*b + li2 + 32*q;
    float2 w[32];
    #pragma unroll
    for (int r2 = 0; r2 < 32; ++r2) w[r2] = lds[(q-16)*264 + li2 + 8*r2];
    stage_twiddle32<1>(w, (2.0f*PI_F) * (float)j2 * (1.0f/32768.0f));
    dft32<1>(w);
    float* o = out + (size_t)(ch0 + c) * XCOR;
    #pragma unroll
    for (int r = 0; r < 32; ++r) {
      int n = j2 + (r << 10);
      int m = 2*n;
      int j1o = (m <= 29999) ? (m + 29999) : ((m >= 35537) ? (m - 35537) : -1);
      if (j1o >= 0) o[j1o] = w[r].x;
      int m2 = m + 1;
      int j2o = (m2 <= 29999) ? (m2 + 29999) : ((m2 >= 35537) ? (m2 - 35537) : -1);
      if (j2o >= 0) o[j2o] = w[r].y;
    }
  }
}

__global__ void diag_kernel(float* out, float vv){ if (threadIdx.x==0 && blockIdx.x==0) out[0] = vv; }

extern "C" void kernel_launch(void* const* d_in, const int* in_sizes, int n_in,
                              void* d_out, int out_size, void* d_ws, size_t ws_size,
                              hipStream_t stream)
{
  const float* d1 = (const float*)d_in[0];
  const float* d2 = (const float*)d_in[1];
  float* out = (float*)d_out;

  const size_t bytesPerCh = 2ULL * 2ULL * (size_t)STR * sizeof(float2);
  int CB = (int)(ws_size / bytesPerCh);
  if (CB > NCH) CB = NCH;
  if (CB < 1) { diag_kernel<<<1,1,0,stream>>>(out, (float)ws_size); return; }

  float2* bufA = (float2*)d_ws;
  float2* bufB = bufA + (size_t)2 * CB * STR;

  for (int ch0 = 0; ch0 < NCH; ch0 += CB) {
    int cb = (NCH - ch0 < CB) ? (NCH - ch0) : CB;
    int nch2 = 2*cb;
    dim3 thr(256);

    // forward: fused stages LG0+LG5 (inputs -> A), then LG10 -> natural-order Z (A -> B)
    fft_fwd_fused2    <<<dim3(nch2*4), thr, 0, stream>>>(d1, d2, bufA, cb, ch0);
    fft_pass32<10,-1> <<<dim3(nch2*4), thr, 0, stream>>>(bufA, bufB);

    // whiten in place on natural-order Z (B)
    whiten_kernel     <<<dim3(nch2), dim3(1024), 0, stream>>>(bufB);

    // cross-spectrum + irfft pack + inverse stage-0 (LDS-free): B -> A
    cross_inv0        <<<dim3(cb*4), thr, 0, stream>>>(bufB, bufA, cb);

    // fused inverse LG5+LG10 (no redundancy, half-slot LDS) + roll + slice: A -> out
    fft_inv_fused3    <<<dim3(cb, 4), thr, 0, stream>>>(bufA, out, ch0);
  }
}

// Round 12
// 1178.111 us; speedup vs baseline: 1.2083x; 1.2083x over previous
//
#include <hip/hip_runtime.h>

#define PI_F 3.14159265358979323846f

#define NCH   1000
#define NPTS  30000
#define NHALF 15000      // NPTS/2 packed complex samples
#define NFFT  32768      // complex FFT length (real length 65536)
#define NBF32 1024       // butterflies per channel per radix-32 pass (NFFT/32)
#define STR   32770      // per-channel stride in complex elements
#define XCOR  59999

#define UC 0.99518472667219693f
#define US 0.09801714032956060f

__device__ __forceinline__ float2 cadd(float2 a, float2 b){ return make_float2(a.x+b.x, a.y+b.y); }
__device__ __forceinline__ float2 csub(float2 a, float2 b){ return make_float2(a.x-b.x, a.y-b.y); }
__device__ __forceinline__ float2 cmul(float2 a, float2 b){ return make_float2(a.x*b.x - a.y*b.y, a.x*b.y + a.y*b.x); }
__device__ __forceinline__ float2 conjmul(float2 a, float2 b){  // conj(a)*b
  return make_float2(a.x*b.x + a.y*b.y, a.x*b.y - a.y*b.x);
}

template<int S>
__device__ __forceinline__ float2 mulIs(float2 z){ return make_float2(-(float)S*z.y, (float)S*z.x); }

// 8-point DFT, ω = e^{S*2πi/8}
template<int S>
__device__ __forceinline__ void dft8(float2 v[8]){
  const float r2 = 0.7071067811865476f;
  const float sf = (float)S;
  float2 ea=cadd(v[0],v[4]), eb=csub(v[0],v[4]);
  float2 ec=cadd(v[2],v[6]), ed=csub(v[2],v[6]);
  float2 oa=cadd(v[1],v[5]), ob=csub(v[1],v[5]);
  float2 oc=cadd(v[3],v[7]), od=csub(v[3],v[7]);
  float2 ied=mulIs<S>(ed), iod=mulIs<S>(od);
  float2 E0=cadd(ea,ec), E2=csub(ea,ec), E1=cadd(eb,ied), E3=csub(eb,ied);
  float2 O0=cadd(oa,oc), O2=csub(oa,oc), O1=cadd(ob,iod), O3=csub(ob,iod);
  float2 T1 = make_float2(r2*(O1.x - sf*O1.y), r2*(O1.y + sf*O1.x));
  float2 T2 = mulIs<S>(O2);
  float2 T3 = make_float2(r2*(-O3.x - sf*O3.y), r2*(sf*O3.x - O3.y));
  v[0]=cadd(E0,O0); v[4]=csub(E0,O0);
  v[1]=cadd(E1,T1); v[5]=csub(E1,T1);
  v[2]=cadd(E2,T2); v[6]=csub(E2,T2);
  v[3]=cadd(E3,T3); v[7]=csub(E3,T3);
}

template<int S>
__device__ __forceinline__ void dft4(float2 v[4]){
  float2 t0=cadd(v[0],v[2]), t1=csub(v[0],v[2]);
  float2 t2=cadd(v[1],v[3]), t3=mulIs<S>(csub(v[1],v[3]));
  v[0]=cadd(t0,t2); v[2]=csub(t0,t2);
  v[1]=cadd(t1,t3); v[3]=csub(t1,t3);
}

// 32-point DFT in registers
template<int S>
__device__ __forceinline__ void dft32(float2 v[32]){
  constexpr float TC[22] = {
    1.f, 0.98078528040323044f, 0.92387953251128674f, 0.83146961230254524f,
    0.70710678118654757f, 0.55557023301960218f, 0.38268343236508978f, 0.19509032201612825f,
    0.f, -0.19509032201612825f, -0.38268343236508978f, -0.55557023301960218f,
    -0.70710678118654757f, -0.83146961230254524f, -0.92387953251128674f, -0.98078528040323044f,
    -1.f, -0.98078528040323044f, -0.92387953251128674f, -0.83146961230254524f,
    -0.70710678118654757f, -0.55557023301960218f };
  constexpr float TS[22] = {
    0.f, 0.19509032201612825f, 0.38268343236508978f, 0.55557023301960218f,
    0.70710678118654757f, 0.83146961230254524f, 0.92387953251128674f, 0.98078528040323044f,
    1.f, 0.98078528040323044f, 0.92387953251128674f, 0.83146961230254524f,
    0.70710678118654757f, 0.55557023301960218f, 0.38268343236508978f, 0.19509032201612825f,
    0.f, -0.19509032201612825f, -0.38268343236508978f, -0.55557023301960218f,
    -0.70710678118654757f, -0.83146961230254524f };
  float2 y[4][8];
  #pragma unroll
  for (int b = 0; b < 4; ++b)
    #pragma unroll
    for (int a = 0; a < 8; ++a) y[b][a] = v[4*a + b];
  #pragma unroll
  for (int b = 0; b < 4; ++b) dft8<S>(y[b]);
  #pragma unroll
  for (int b = 1; b < 4; ++b)
    #pragma unroll
    for (int k1 = 1; k1 < 8; ++k1) {
      int m = b*k1;
      float2 w = make_float2(TC[m], (float)S * TS[m]);
      y[b][k1] = cmul(y[b][k1], w);
    }
  #pragma unroll
  for (int k1 = 0; k1 < 8; ++k1) {
    float2 z[4] = { y[0][k1], y[1][k1], y[2][k1], y[3][k1] };
    dft4<S>(z);
    #pragma unroll
    for (int k2 = 0; k2 < 4; ++k2) v[k1 + 8*k2] = z[k2];
  }
}

template<int S>
__device__ __forceinline__ void stage_twiddle32(float2 v[32], float ang){
  float s1,c1,s8,c8;
  __sincosf(ang, &s1, &c1);
  __sincosf(8.f*ang, &s8, &c8);
  float2 w1 = make_float2(c1, s1), w8 = make_float2(c8, s8);
  float2 w16 = cmul(w8, w8), w24 = cmul(w16, w8);
  float2 base[4] = { make_float2(1.f, 0.f), w8, w16, w24 };
  #pragma unroll
  for (int m = 0; m < 4; ++m) {
    float2 wr = base[m];
    if (m > 0) v[8*m] = cmul(v[8*m], wr);
    #pragma unroll
    for (int l = 1; l < 8; ++l) { wr = cmul(wr, w1); v[8*m+l] = cmul(v[8*m+l], wr); }
  }
}

// ========== FWD FUSED: stages LG0 + LG5 through LDS (verified round 7) ==========
__global__ __launch_bounds__(256) void fft_fwd_fused(const float* __restrict__ d1, const float* __restrict__ d2,
                                                     float2* __restrict__ out, int cb, int ch0)
{
  __shared__ float2 lds[256*33];   // 67.6 KB, stride-33 rows
  const int bid = blockIdx.x;
  const int c = bid >> 2, b = bid & 3;
  const int t = threadIdx.x;
  const float* src = (c < cb) ? (d1 + (size_t)(ch0 + c) * NPTS)
                              : (d2 + (size_t)(ch0 + c - cb) * NPTS);
  const float2* src2 = reinterpret_cast<const float2*>(src);

  const int j1 = 8*b + (t & 7) + 32*(t >> 3);
  float2 v[32];
  #pragma unroll
  for (int r = 0; r < 32; ++r) {
    int m = j1 + (r << 10);
    v[r] = (m < NHALF) ? src2[m] : make_float2(0.f, 0.f);
  }
  dft32<-1>(v);
  #pragma unroll
  for (int r = 0; r < 32; ++r) lds[t*33 + r] = v[r];
  __syncthreads();

  const int d = t >> 5, jm = t & 31;
  #pragma unroll
  for (int r = 0; r < 32; ++r) v[r] = lds[(d + 8*r)*33 + jm];
  stage_twiddle32<-1>(v, -(2.0f*PI_F) * (float)jm * (1.0f/1024.0f));
  dft32<-1>(v);
  const int j2 = 256*b + t;
  float2* dst = out + (size_t)c * STR + ((j2 >> 5) << 10) + jm;
  #pragma unroll
  for (int r = 0; r < 32; ++r) dst[(size_t)(r << 5)] = v[r];
}

// ---------- generic Stockham radix-32 pass, Ns = 2^LG ----------
template<int LG, int S>
__global__ __launch_bounds__(256) void fft_pass32(const float2* __restrict__ in, float2* __restrict__ out)
{
  int tid = blockIdx.x*256 + threadIdx.x;
  int c = tid >> 10;
  int j = tid & (NBF32-1);
  const float2* src = in + (size_t)c * STR;
  float2 v[32];
  #pragma unroll
  for (int r = 0; r < 32; ++r) v[r] = src[j + (r << 10)];
  constexpr int NS = 1 << LG;
  int jm = j & (NS - 1);
  if constexpr (LG > 0) {
    float ang = (float)S * (2.0f*PI_F) * (float)jm / (float)(NS*32);
    stage_twiddle32<S>(v, ang);
  }
  dft32<S>(v);
  int idxD = ((j >> LG) << (LG+5)) + jm;
  float2* dst = out + (size_t)c * STR + idxD;
  #pragma unroll
  for (int r = 0; r < 32; ++r) dst[(size_t)(r << LG)] = v[r];
}

// ---------- whitening: round-2 structure + twiddle/taper complex recurrences (VALU cut) ----------
__device__ __forceinline__ int padidx(int m){ return m + (m >> 5); }

__global__ __launch_bounds__(1024) void whiten_kernel(float2* __restrict__ buf)
{
  const int ch = blockIdx.x;
  const int t  = threadIdx.x;
  float2* Z = buf + (size_t)ch * STR;
  __shared__ float s[33793];     // 32769 magnitudes, padded every 32
  __shared__ float wsums[16];

  float2 X[33];
  // phase 1: unpack X[k]; twiddle w(k)=e^{-i pi k/32768} via recurrence (step e^{-i pi/32})
  {
    float s0, c0; __sincosf(-PI_F*(float)t*(1.0f/32768.0f), &s0, &c0);
    float2 uw = make_float2(c0, s0);
    const float2 uwstep = make_float2(UC, -US);
    #pragma unroll
    for (int i = 0; i < 33; ++i) {
      int k = i*1024 + t;
      if (i < 32 || t == 0) {
        float2 zk = Z[k & (NFFT-1)];
        float2 zn = Z[(NFFT - k) & (NFFT-1)];
        float2 xe = make_float2(0.5f*(zk.x+zn.x), 0.5f*(zk.y-zn.y));
        float2 xh = make_float2(0.5f*(zk.x-zn.x), 0.5f*(zk.y+zn.y));
        float2 xo = make_float2(xh.y, -xh.x);
        X[i] = cadd(xe, cmul(uw, xo));
        s[padidx(k)] = sqrtf(X[i].x*X[i].x + X[i].y*X[i].y);
      }
      uw = cmul(uw, uwstep);
    }
  }
  __syncthreads();

  // phase 2: block-wide inclusive cumsum of magnitudes (in place in LDS)
  const int base = t*32;
  float sum = 0.f;
  #pragma unroll
  for (int q = 0; q < 32; ++q) sum += s[padidx(base+q)];
  if (t == 1023) sum += s[padidx(32768)];
  const int lane = t & 63, wid = t >> 6;
  float v = sum;
  #pragma unroll
  for (int off = 1; off < 64; off <<= 1) {
    float u = __shfl_up(v, off);
    if (lane >= off) v += u;
  }
  if (lane == 63) wsums[wid] = v;
  __syncthreads();
  float wexcl = 0.f;
  for (int w = 0; w < 16; ++w) wexcl += (w < wid) ? wsums[w] : 0.f;
  float run = wexcl + (v - sum);
  #pragma unroll
  for (int q = 0; q < 32; ++q) {
    int idx = padidx(base+q);
    run += s[idx];
    s[idx] = run;
  }
  if (t == 1023) { int idx = padidx(32768); run += s[idx]; s[idx] = run; }
  __syncthreads();

  // phase 3: box-mean gain + tapers; hi-taper cos^2 via recurrence (step e^{+i 1024 pi/39320})
  const float a0 = s[padidx(0)];
  const float alast = s[padidx(32768)] - s[padidx(32767)];
  {
    float su, cu; __sincosf(((float)t - 13108.0f)*(PI_F/39320.0f), &su, &cu);
    float2 tu = make_float2(cu, su);
    float tss, tcc; __sincosf(1024.0f*(PI_F/39320.0f), &tss, &tcc);
    const float2 tustep = make_float2(tcc, tss);
    #pragma unroll
    for (int i = 0; i < 33; ++i) {
      int k = i*1024 + t;
      if (i < 32 || t == 0) {
        int hi = k + 327; if (hi > 32768) hi = 32768;
        int lom1 = k - 328;
        float Shi = s[padidx(hi)];
        float Slo = (lom1 >= 0) ? s[padidx(lom1)] : 0.f;
        float lc = (k < 327) ? (float)(327 - k) : 0.f;
        float rc = (k > 32441) ? (float)(k - 32441) : 0.f;
        float smoothed = (lc*a0 + (Shi - Slo) + rc*alast) * (1.0f/655.0f);
        float2 wv;
        if (smoothed > 0.f) {
          float inv = 1.0f / smoothed;
          wv = make_float2(X[i].x*inv, X[i].y*inv);
        } else wv = make_float2(0.f, 0.f);
        float tp = 1.0f;
        if (k < 131)        { float sn = __sinf((float)k * (PI_F/260.0f)); tp = sn*sn; }
        else if (k >= 13108) tp = tu.x*tu.x;
        wv.x *= tp; wv.y *= tp;
        Z[k] = wv;
      }
      tu = cmul(tu, tustep);
    }
  }
}

// ================= CROSS_INV0_PAIR (round-8/10 verified; reads every W bin exactly once) =================
__device__ __forceinline__ float2 pack_zinv(float2 Ck, float2 Cm, float2 pw){
  const float scale = 1.0f/32768.0f;
  float2 xe = make_float2(0.5f*(Ck.x+Cm.x), 0.5f*(Ck.y-Cm.y));
  float2 d  = make_float2(0.5f*(Ck.x-Cm.x), 0.5f*(Ck.y+Cm.y));
  float2 xo = cmul(pw, d);
  return make_float2((xe.x - xo.y)*scale, (xe.y + xo.x)*scale);
}

__global__ __launch_bounds__(256) void cross_inv0_pair(const float2* __restrict__ W,
                                                       float2* __restrict__ out0, int cb)
{
  __shared__ float2 zbs[256*33];   // 67.6 KB zB stash (stride 33)
  const int bid = blockIdx.x;
  const int c = bid >> 1;
  const int t = threadIdx.x;
  const int p = ((bid & 1) << 8) + t;      // pair index 0..511
  const float2* W1 = W + (size_t)c * STR;
  const float2* W2 = W + (size_t)(cb + c) * STR;
  const float scale = 1.0f/32768.0f;
  float2 zA[32];
  float2* zB = zbs + t*33;

  if (p != 0) {
    const int q = 1024 - p;
    float sp, cp; __sincosf(PI_F*(float)p*(1.0f/32768.0f), &sp, &cp);
    float2 pw = make_float2(cp, sp);
    const float2 pstep = make_float2(UC, US);    // e^{+i pi/32}
    #pragma unroll
    for (int r = 0; r < 32; ++r) {
      int m  = p + (r << 10);
      int mm = q + ((31 - r) << 10);             // = 32768 - m
      float2 Ck = conjmul(W1[m],  W2[m]);
      float2 Cm = conjmul(W1[mm], W2[mm]);
      zA[r]    = pack_zinv(Ck, Cm, pw);
      zB[31-r] = pack_zinv(Cm, Ck, make_float2(-pw.x, pw.y));
      pw = cmul(pw, pstep);
    }
  } else {
    {
      float2 Ck = conjmul(W1[0], W2[0]);
      float2 Cm = conjmul(W1[32768], W2[32768]);
      zA[0] = pack_zinv(Ck, Cm, make_float2(1.f, 0.f));
    }
    #pragma unroll
    for (int i = 1; i < 16; ++i) {
      int k = i << 10, km = 32768 - k;
      float2 Ck = conjmul(W1[k],  W2[k]);
      float2 Cm = conjmul(W1[km], W2[km]);
      float sp2, cp2; __sincosf(PI_F*(float)k*(1.0f/32768.0f), &sp2, &cp2);
      zA[i]    = pack_zinv(Ck, Cm, make_float2(cp2, sp2));
      zA[32-i] = pack_zinv(Cm, Ck, make_float2(-cp2, sp2));
    }
    {
      float2 Ck = conjmul(W1[16384], W2[16384]);
      zA[16] = make_float2(Ck.x*scale, -Ck.y*scale);   // Zinv[16384] = conj(C)/N
    }
    #pragma unroll
    for (int i = 0; i < 16; ++i) {
      int k = (i << 10) + 512, km = 32768 - k;
      float2 Ck = conjmul(W1[k],  W2[k]);
      float2 Cm = conjmul(W1[km], W2[km]);
      float sp2, cp2; __sincosf(PI_F*(float)k*(1.0f/32768.0f), &sp2, &cp2);
      zB[i]    = pack_zinv(Ck, Cm, make_float2(cp2, sp2));
      zB[31-i] = pack_zinv(Cm, Ck, make_float2(-cp2, sp2));
    }
  }

  dft32<1>(zA);
  {
    float4* o4 = reinterpret_cast<float4*>(out0 + (size_t)c*STR + (size_t)p*32);
    #pragma unroll
    for (int r = 0; r < 32; r += 2)
      o4[r>>1] = make_float4(zA[r].x, zA[r].y, zA[r+1].x, zA[r+1].y);
  }
  {
    float2 zq[32];
    #pragma unroll
    for (int r = 0; r < 32; ++r) zq[r] = zB[r];
    dft32<1>(zq);
    const int jout = (p == 0) ? 512 : (1024 - p);
    float4* o4 = reinterpret_cast<float4*>(out0 + (size_t)c*STR + (size_t)jout*32);
    #pragma unroll
    for (int r = 0; r < 32; r += 2)
      o4[r>>1] = make_float4(zq[r].x, zq[r].y, zq[r+1].x, zq[r+1].y);
  }
}

// ---------- inverse final pass (Ns=1024, radix-32), fused unpack + roll + slice (verified r7) ----------
__global__ __launch_bounds__(256) void fft_inv_final32(const float2* __restrict__ in, float* __restrict__ out, int ch0)
{
  int tid = blockIdx.x*256 + threadIdx.x;
  int c = tid >> 10;
  int j = tid & (NBF32-1);
  const float2* src = in + (size_t)c * STR;
  float2 v[32];
  #pragma unroll
  for (int r = 0; r < 32; ++r) v[r] = src[j + (r << 10)];
  float ang = (2.0f*PI_F) * (float)j * (1.0f/32768.0f);
  stage_twiddle32<1>(v, ang);
  dft32<1>(v);
  float* o = out + (size_t)(ch0 + c) * XCOR;
  #pragma unroll
  for (int r = 0; r < 32; ++r) {
    int n = j + (r << 10);
    int m = 2*n;
    int j1 = (m <= 29999) ? (m + 29999) : ((m >= 35537) ? (m - 35537) : -1);
    if (j1 >= 0) o[j1] = v[r].x;
    int m2 = m + 1;
    int j2 = (m2 <= 29999) ? (m2 + 29999) : ((m2 >= 35537) ? (m2 - 35537) : -1);
    if (j2 >= 0) o[j2] = v[r].y;
  }
}

__global__ void diag_kernel(float* out, float vv){ if (threadIdx.x==0 && blockIdx.x==0) out[0] = vv; }

extern "C" void kernel_launch(void* const* d_in, const int* in_sizes, int n_in,
                              void* d_out, int out_size, void* d_ws, size_t ws_size,
                              hipStream_t stream)
{
  const float* d1 = (const float*)d_in[0];
  const float* d2 = (const float*)d_in[1];
  float* out = (float*)d_out;

  const size_t bytesPerCh = 2ULL * 2ULL * (size_t)STR * sizeof(float2);
  int CB = (int)(ws_size / bytesPerCh);
  if (CB > NCH) CB = NCH;
  if (CB < 1) { diag_kernel<<<1,1,0,stream>>>(out, (float)ws_size); return; }

  float2* bufA = (float2*)d_ws;
  float2* bufB = bufA + (size_t)2 * CB * STR;

  for (int ch0 = 0; ch0 < NCH; ch0 += CB) {
    int cb = (NCH - ch0 < CB) ? (NCH - ch0) : CB;
    int nch2 = 2*cb;
    dim3 thr(256);

    // forward: fused stages LG0+LG5 (inputs -> A), then LG10 -> natural-order Z (A -> B)
    fft_fwd_fused     <<<dim3(nch2*4), thr, 0, stream>>>(d1, d2, bufA, cb, ch0);
    fft_pass32<10,-1> <<<dim3(nch2*4), thr, 0, stream>>>(bufA, bufB);

    // whiten in place on natural-order Z (B)
    whiten_kernel     <<<dim3(nch2), dim3(1024), 0, stream>>>(bufB);

    // pair-ownership cross-spectrum + irfft pack + inverse stage-0: B -> A
    cross_inv0_pair   <<<dim3(cb*2), thr, 0, stream>>>(bufB, bufA, cb);

    // inverse: middle pass LG=5 (A -> B), final LG=10 fused with roll + slice (B -> out)
    fft_pass32<5,1>   <<<dim3(cb*4), thr, 0, stream>>>(bufA, bufB);
    fft_inv_final32   <<<dim3(cb*4), thr, 0, stream>>>(bufB, out, ch0);
  }
}